// Round 1
// baseline (175.008 us; speedup 1.0000x reference)
//
#include <hip/hip_runtime.h>
#include <math.h>

// Problem constants (fixed by setup_inputs)
#define D 1024
#define B 32
#define N 1024          // patches per image (32x32)
#define SIDE 32
#define OUT 512
#define NLAYER 4
#define TAU_INV (1.0f/0.07f)
#define EPS_NORM 1e-12f

// ---------------------------------------------------------------------------
// Kernel A: inverse L2 norms of the 16 weight rows (4 layers x {cls0,cls1,seg0,seg1})
// grid: 16 blocks x 64 threads (one wave per row)
// ws_inv[l*4 + 0..1] = 1/||w_cls_l[row]||, ws_inv[l*4 + 2..3] = 1/||w_seg_l[row]||
// ---------------------------------------------------------------------------
__global__ void wnorm_kernel(const float* wc0, const float* ws0,
                             const float* wc1, const float* ws1,
                             const float* wc2, const float* ws2,
                             const float* wc3, const float* ws3,
                             float* ws_inv) {
    int id = blockIdx.x;          // 0..15
    int l = id >> 2;
    int k = id & 3;               // 0,1 = cls rows ; 2,3 = seg rows
    const float* wc; const float* wsg;
    if      (l == 0) { wc = wc0; wsg = ws0; }
    else if (l == 1) { wc = wc1; wsg = ws1; }
    else if (l == 2) { wc = wc2; wsg = ws2; }
    else             { wc = wc3; wsg = ws3; }
    const float* row = (k < 2) ? (wc + (k & 1) * D) : (wsg + (k & 1) * D);

    int lane = threadIdx.x;       // 0..63
    float s = 0.f;
#pragma unroll
    for (int kk = 0; kk < 4; ++kk) {
        const float4 v = *reinterpret_cast<const float4*>(row + kk * 256 + lane * 4);
        s += v.x * v.x + v.y * v.y + v.z * v.z + v.w * v.w;
    }
#pragma unroll
    for (int m = 32; m; m >>= 1) s += __shfl_xor(s, m);
    if (lane == 0) ws_inv[id] = 1.0f / fmaxf(sqrtf(s), EPS_NORM);
}

// ---------------------------------------------------------------------------
// Kernel B: cls logits. One wave per (l,b) row; 128 waves -> 32 blocks x 256.
// out[(l*B + b)*2 + c] = dot(cls, wcls_c) * inv||cls|| * inv||wcls_c|| / tau
// ---------------------------------------------------------------------------
__global__ void cls_kernel(const float* c0, const float* wc0,
                           const float* c1, const float* wc1,
                           const float* c2, const float* wc2,
                           const float* c3, const float* wc3,
                           const float* ws_inv, float* out) {
    int wid = blockIdx.x * 4 + (threadIdx.x >> 6);   // 0..127
    int lane = threadIdx.x & 63;
    int l = wid >> 5;
    int b = wid & 31;
    const float* cls; const float* wc;
    if      (l == 0) { cls = c0; wc = wc0; }
    else if (l == 1) { cls = c1; wc = wc1; }
    else if (l == 2) { cls = c2; wc = wc2; }
    else             { cls = c3; wc = wc3; }
    const float* x = cls + (size_t)b * D;

    float sxx = 0.f, s0 = 0.f, s1 = 0.f;
#pragma unroll
    for (int kk = 0; kk < 4; ++kk) {
        int off = kk * 256 + lane * 4;
        const float4 v  = *reinterpret_cast<const float4*>(x + off);
        const float4 a  = *reinterpret_cast<const float4*>(wc + off);
        const float4 bb = *reinterpret_cast<const float4*>(wc + D + off);
        sxx += v.x * v.x + v.y * v.y + v.z * v.z + v.w * v.w;
        s0  += v.x * a.x + v.y * a.y + v.z * a.z + v.w * a.w;
        s1  += v.x * bb.x + v.y * bb.y + v.z * bb.z + v.w * bb.w;
    }
#pragma unroll
    for (int m = 32; m; m >>= 1) {
        sxx += __shfl_xor(sxx, m);
        s0  += __shfl_xor(s0, m);
        s1  += __shfl_xor(s1, m);
    }
    if (lane == 0) {
        float invx = 1.0f / fmaxf(sqrtf(sxx), EPS_NORM);
        out[((size_t)l * B + b) * 2 + 0] = s0 * invx * ws_inv[l * 4 + 0] * TAU_INV;
        out[((size_t)l * B + b) * 2 + 1] = s1 * invx * ws_inv[l * 4 + 1] * TAU_INV;
    }
}

// ---------------------------------------------------------------------------
// Kernel C: seg probabilities. One wave per (l,b,n) patch row.
// rows = 4*32*1024 = 131072 -> 32768 blocks x 256 threads (4 waves/block).
// Writes probs laid out as [L][B][2][N] (image-contiguous per class).
// ---------------------------------------------------------------------------
__global__ __launch_bounds__(256) void seg_kernel(
        const float* p0, const float* w0,
        const float* p1, const float* w1,
        const float* p2, const float* w2,
        const float* p3, const float* w3,
        const float* ws_inv, float* probs) {
    int wid = blockIdx.x * 4 + (threadIdx.x >> 6);   // 0..131071
    int lane = threadIdx.x & 63;
    int l = wid >> 15;           // B*N = 32768 rows per layer
    int rem = wid & 32767;       // b*N + n
    const float* patch; const float* wsg;
    if      (l == 0) { patch = p0; wsg = w0; }
    else if (l == 1) { patch = p1; wsg = w1; }
    else if (l == 2) { patch = p2; wsg = w2; }
    else             { patch = p3; wsg = w3; }
    const float* x = patch + (size_t)rem * D;

    float sxx = 0.f, s0 = 0.f, s1 = 0.f;
#pragma unroll
    for (int kk = 0; kk < 4; ++kk) {
        int off = kk * 256 + lane * 4;
        const float4 v  = *reinterpret_cast<const float4*>(x + off);
        const float4 a  = *reinterpret_cast<const float4*>(wsg + off);
        const float4 bb = *reinterpret_cast<const float4*>(wsg + D + off);
        sxx += v.x * v.x + v.y * v.y + v.z * v.z + v.w * v.w;
        s0  += v.x * a.x + v.y * a.y + v.z * a.z + v.w * a.w;
        s1  += v.x * bb.x + v.y * bb.y + v.z * bb.z + v.w * bb.w;
    }
#pragma unroll
    for (int m = 32; m; m >>= 1) {
        sxx += __shfl_xor(sxx, m);
        s0  += __shfl_xor(s0, m);
        s1  += __shfl_xor(s1, m);
    }
    if (lane == 0) {
        float invx = 1.0f / fmaxf(sqrtf(sxx), EPS_NORM);
        float l0 = s0 * invx * ws_inv[l * 4 + 2] * TAU_INV;
        float l1 = s1 * invx * ws_inv[l * 4 + 3] * TAU_INV;
        float pr0 = 1.0f / (1.0f + __expf(l1 - l0));
        float pr1 = 1.0f / (1.0f + __expf(l0 - l1));
        int b = rem >> 10, n = rem & 1023;
        float* o = probs + ((size_t)(l * B + b) * 2) * N + n;
        o[0] = pr0;
        o[N] = pr1;
    }
}

// ---------------------------------------------------------------------------
// Kernel D: bilinear 16x upsample 32x32 -> 512x512 per image.
// 256 images (L*B*2), 8 row-chunks of 64 rows each -> 2048 blocks x 256.
// Stage 1: build y-interpolated rowbuf[64][32] in LDS (src image is L1/L2 hot).
// Stage 2: each thread emits float4 outputs with inline x-weights.
// Half-pixel mapping src = (dst+0.5)/16 - 0.5 with edge clamp.
// ---------------------------------------------------------------------------
__global__ __launch_bounds__(256) void upsample_kernel(const float* probs, float* out) {
    __shared__ float rowbuf[64 * 32];

    int img   = blockIdx.x >> 3;     // 0..255
    int chunk = blockIdx.x & 7;      // 0..7 (64 rows each)
    const float* S = probs + (size_t)img * (SIDE * SIDE);

    // Stage 1: rowbuf[r][x] = lerp_y(S) for output rows gy = chunk*64 + r
    for (int e = threadIdx.x; e < 64 * 32; e += 256) {
        int r = e >> 5;
        int xs = e & 31;
        int gy = chunk * 64 + r;
        float fy = ((float)gy + 0.5f) * 0.0625f - 0.5f;
        fy = fmaxf(fy, 0.0f);
        int y0 = min((int)fy, SIDE - 1);
        int y1 = min(y0 + 1, SIDE - 1);
        float wy = fy - (float)y0;
        float a = S[y0 * SIDE + xs];
        float b = S[y1 * SIDE + xs];
        rowbuf[e] = a + wy * (b - a);
    }
    __syncthreads();

    // Stage 2: 64 rows x 128 float4 per row = 8192 float4 per block
    float4* obase = reinterpret_cast<float4*>(out) + (size_t)img * (OUT * OUT / 4);
#pragma unroll 4
    for (int it = 0; it < 32; ++it) {
        int idx = it * 256 + threadIdx.x;    // 0..8191
        int r   = idx >> 7;                  // row within chunk
        int xv  = idx & 127;                 // float4 index within row
        const float* rb = rowbuf + r * 32;
        float4 o;
#pragma unroll
        for (int j = 0; j < 4; ++j) {
            int xx = xv * 4 + j;
            float fx = ((float)xx + 0.5f) * 0.0625f - 0.5f;
            fx = fmaxf(fx, 0.0f);
            int x0 = min((int)fx, SIDE - 1);
            int x1 = min(x0 + 1, SIDE - 1);
            float wx = fx - (float)x0;
            float r0 = rb[x0];
            float r1 = rb[x1];
            (&o.x)[j] = r0 + wx * (r1 - r0);
        }
        int gy = chunk * 64 + r;
        obase[(size_t)gy * (OUT / 4) + xv] = o;
    }
}

// ---------------------------------------------------------------------------
extern "C" void kernel_launch(void* const* d_in, const int* in_sizes, int n_in,
                              void* d_out, int out_size, void* d_ws, size_t ws_size,
                              hipStream_t stream) {
    // Input order: per layer l in {5,11,17,23}: cls, patch, w_cls, w_seg
    const float* cls[4];  const float* patch[4];
    const float* wcls[4]; const float* wseg[4];
    for (int l = 0; l < 4; ++l) {
        cls[l]   = (const float*)d_in[4 * l + 0];
        patch[l] = (const float*)d_in[4 * l + 1];
        wcls[l]  = (const float*)d_in[4 * l + 2];
        wseg[l]  = (const float*)d_in[4 * l + 3];
    }
    float* out = (float*)d_out;            // [4,32,2] cls logits then [4,32,2,512,512]
    float* seg_out = out + NLAYER * B * 2; // offset 256 floats

    float* wsf      = (float*)d_ws;
    float* ws_inv   = wsf;                 // 16 floats
    float* ws_probs = wsf + 64;            // [4][32][2][1024] = 262144 floats (1 MB)

    wnorm_kernel<<<16, 64, 0, stream>>>(wcls[0], wseg[0], wcls[1], wseg[1],
                                        wcls[2], wseg[2], wcls[3], wseg[3], ws_inv);

    cls_kernel<<<32, 256, 0, stream>>>(cls[0], wcls[0], cls[1], wcls[1],
                                       cls[2], wcls[2], cls[3], wcls[3],
                                       ws_inv, out);

    seg_kernel<<<32768, 256, 0, stream>>>(patch[0], wseg[0], patch[1], wseg[1],
                                          patch[2], wseg[2], patch[3], wseg[3],
                                          ws_inv, ws_probs);

    upsample_kernel<<<2048, 256, 0, stream>>>(ws_probs, seg_out);
}